// Round 18
// baseline (166.948 us; speedup 1.0000x reference)
//
#include <hip/hip_runtime.h>
#include <stdint.h>

#define NH 16
#define NN 4096

typedef __attribute__((ext_vector_type(8))) short bf16x8;
typedef __attribute__((ext_vector_type(4))) short bf16x4;
typedef __attribute__((ext_vector_type(4))) float f32x4;
typedef __attribute__((ext_vector_type(16))) float f32x16;
typedef unsigned short u16;
typedef unsigned int u32;
typedef __attribute__((ext_vector_type(4))) u32 u32x4;

__device__ __forceinline__ u16 f2bf(float f) {
  u32 u = __float_as_uint(f);
  return (u16)((u + 0x7FFFu + ((u >> 16) & 1u)) >> 16);
}
__device__ __forceinline__ float bf2f(u16 v) {
  return __uint_as_float(((u32)v) << 16);
}

#define GLD16(gp, lp)                                              \
  __builtin_amdgcn_global_load_lds(                                \
      (__attribute__((address_space(1))) void*)(gp),               \
      (__attribute__((address_space(3))) void*)(lp), 16, 0, 0)

// ---------------- prep: fused weight transposes (z<4) + x f32->bf16 (z=4,5) ----------------
__global__ __launch_bounds__(256) void prep(const float* __restrict__ x,
                                            const float* __restrict__ Wq,
                                            const float* __restrict__ Wk,
                                            const float* __restrict__ Wv,
                                            const float* __restrict__ Wo,
                                            u16* __restrict__ xb,
                                            u16* __restrict__ Wqt, u16* __restrict__ Wkt,
                                            u16* __restrict__ Wvt, u16* __restrict__ Wot) {
  __shared__ float tile[64][65];
  int z = blockIdx.z;
  int tid = threadIdx.x;
  if (z >= 4) {
    int bi = (z - 4) * 256 + blockIdx.y * 16 + blockIdx.x;
    size_t base = (size_t)bi * 8192;
#pragma unroll
    for (int k = 0; k < 4; ++k) {
      size_t i = base + (size_t)k * 2048 + tid * 8;
      float4 a = *(const float4*)(x + i);
      float4 b = *(const float4*)(x + i + 4);
      uint4 o;
      o.x = (u32)f2bf(a.x) | ((u32)f2bf(a.y) << 16);
      o.y = (u32)f2bf(a.z) | ((u32)f2bf(a.w) << 16);
      o.z = (u32)f2bf(b.x) | ((u32)f2bf(b.y) << 16);
      o.w = (u32)f2bf(b.z) | ((u32)f2bf(b.w) << 16);
      *(uint4*)(xb + i) = o;
    }
    return;
  }
  const float* src;
  u16* dst;
  float scale = 1.0f;
  if (z == 0) { src = Wq; dst = Wqt; scale = 0.125f * 1.4426950408889634f; }
  else if (z == 1) { src = Wk; dst = Wkt; }
  else if (z == 2) { src = Wv; dst = Wvt; }
  else { src = Wo; dst = Wot; }
  int tx = tid & 63, ty = tid >> 6;
  int c0 = blockIdx.x * 64, r0 = blockIdx.y * 64;
#pragma unroll
  for (int i = ty; i < 64; i += 4)
    tile[i][tx] = src[(size_t)(r0 + i) * 1024 + c0 + tx];
  __syncthreads();
#pragma unroll
  for (int i = ty; i < 64; i += 4)
    dst[(size_t)(c0 + i) * 1024 + r0 + tx] = f2bf(tile[tx][i] * scale);
}

// ---------------- fused QKV GEMM: [4096][1024] @ Wt[3072][1024]^T ----------------
// Bijective XCD swizzle (768 blocks = 8 x 96). V (sec==2): acc -> swizzled LDS tile ->
// coalesced V^T stores (quad-interleaved n).
__global__ __launch_bounds__(256) void gemm_qkv(const u16* __restrict__ A,
                                                const u16* __restrict__ Bt,
                                                u16* __restrict__ Qb, u16* __restrict__ Kb,
                                                u16* __restrict__ Vth) {
  __shared__ __align__(16) u16 SH[16384];  // 32KB
  u16* A_lds = SH;
  u16* B_lds = SH + 8192;
  const int tid = threadIdx.x;
  const int l = tid & 63, w = tid >> 6;
  const int g = l >> 4, c = l & 15;
  const int wr = w >> 1, wc = w & 1;
  const int flat = blockIdx.x + blockIdx.y * 24;
  const int p = (flat & 7) * 96 + (flat >> 3);
  const int m0 = (p / 24) * 128, n0 = (p % 24) * 128;

  const int srow = tid >> 2;
  const u32 sswz = (u32)(((tid & 3) * 16) ^ ((srow & 3) << 4));
  const char* Ag = (const char*)A + (size_t)(m0 + srow) * 2048 + sswz;
  const char* Bg = (const char*)Bt + (size_t)(n0 + srow) * 2048 + sswz;
  const u32 ldsb = (u32)(w * 1024);

#define GSTAGE(buf, ks_)                                                          \
  do {                                                                            \
    u32 koff_ = (u32)(ks_) * 64;                                                  \
    _Pragma("unroll") for (int p_ = 0; p_ < 2; ++p_) {                            \
      GLD16(Ag + koff_ + (size_t)p_ * 64 * 2048,                                  \
            (char*)A_lds + (buf) * 8192 + p_ * 4096 + ldsb);                      \
      GLD16(Bg + koff_ + (size_t)p_ * 64 * 2048,                                  \
            (char*)B_lds + (buf) * 8192 + p_ * 4096 + ldsb);                      \
    }                                                                             \
  } while (0)

  f32x4 acc[4][4];
#pragma unroll
  for (int i = 0; i < 4; ++i)
#pragma unroll
    for (int j = 0; j < 4; ++j) acc[i][j] = (f32x4){0.f, 0.f, 0.f, 0.f};

  int cur = 0;
  GSTAGE(0, 0);
  for (int ks = 0; ks < 32; ++ks) {
    GSTAGE(cur ^ 1, (ks + 1) & 31);
    asm volatile("s_waitcnt vmcnt(4)" ::: "memory");
    __builtin_amdgcn_s_barrier();
    __builtin_amdgcn_sched_barrier(0);
    const char* Ac = (const char*)A_lds + cur * 8192;
    const char* Bc = (const char*)B_lds + cur * 8192;
    bf16x8 af[4], bfr[4];
#pragma unroll
    for (int i = 0; i < 4; ++i) {
      int row = wr * 64 + i * 16 + c;
      af[i] = *(const bf16x8*)(Ac + row * 64 + ((g * 16) ^ ((row & 3) << 4)));
    }
#pragma unroll
    for (int j = 0; j < 4; ++j) {
      int row = wc * 64 + j * 16 + c;
      bfr[j] = *(const bf16x8*)(Bc + row * 64 + ((g * 16) ^ ((row & 3) << 4)));
    }
    __builtin_amdgcn_s_setprio(1);
#pragma unroll
    for (int i = 0; i < 4; ++i)
#pragma unroll
      for (int j = 0; j < 4; ++j)
        acc[i][j] = __builtin_amdgcn_mfma_f32_16x16x32_bf16(af[i], bfr[j], acc[i][j], 0, 0, 0);
    __builtin_amdgcn_s_setprio(0);
    asm volatile("s_waitcnt lgkmcnt(0)" ::: "memory");
    __builtin_amdgcn_s_barrier();
    __builtin_amdgcn_sched_barrier(0);
    cur ^= 1;
  }
#undef GSTAGE

  const int sec = n0 >> 10;  // block-uniform: 0=Q, 1=K, 2=V
  if (sec < 2) {
#pragma unroll
    for (int i = 0; i < 4; ++i)
#pragma unroll
      for (int j = 0; j < 4; ++j)
#pragma unroll
        for (int r = 0; r < 4; ++r) {
          int m = m0 + wr * 64 + i * 16 + g * 4 + r;
          int cc = (n0 + wc * 64 + j * 16 + c) & 1023;
          u16 v = f2bf(acc[i][j][r]);
          if (sec == 0) Qb[(size_t)m * 1024 + cc] = v;
          else Kb[(size_t)m * 1024 + cc] = v;
        }
  } else {
    // V^T via LDS transpose (loop's final barrier already synced; SH is free).
    const int gq = ((g & 1) << 1) | (g >> 1);  // quad-swap 1<->2 for V n-order
    const int cc0 = n0 & 1023;
#pragma unroll
    for (int i = 0; i < 4; ++i)
#pragma unroll
      for (int j = 0; j < 4; ++j)
#pragma unroll
        for (int r = 0; r < 4; ++r) {
          int cl = wc * 64 + j * 16 + c;            // local col (d)
          int mql = wr * 64 + i * 16 + gq * 4 + r;  // local n, quad-interleaved
          SH[cl * 128 + (mql ^ ((cl & 15) << 3))] = f2bf(acc[i][j][r]);
        }
    __syncthreads();
#pragma unroll
    for (int p2 = 0; p2 < 4; ++p2) {
      int row = p2 * 32 + (tid >> 3);
#pragma unroll
      for (int half = 0; half < 2; ++half) {
        int mq = (tid & 7) * 8 + half * 64;
        bf16x8 vv = *(const bf16x8*)&SH[row * 128 + (mq ^ ((row & 15) << 3))];
        *(bf16x8*)(Vth + (size_t)(cc0 + row) * 4096 + m0 + mq) = vv;
      }
    }
  }
}

// ---------------- out-proj GEMM fallback (non-split): 128x128, bf16 A ----------------
__global__ __launch_bounds__(256) void gemm_out256(const u16* __restrict__ A,
                                                   const u16* __restrict__ Bt,
                                                   float* __restrict__ out,
                                                   const float* __restrict__ bias) {
  __shared__ __align__(16) u16 SH[16384];  // 32KB
  u16* A_lds = SH;
  u16* B_lds = SH + 8192;
  const int tid = threadIdx.x;
  const int l = tid & 63, w = tid >> 6;
  const int g = l >> 4, c = l & 15;
  const int wr = w >> 1, wc = w & 1;
  const int flat = blockIdx.x + blockIdx.y * 8;
  const int p = (flat & 7) * 32 + (flat >> 3);
  const int m0 = (p >> 3) * 128, n0 = (p & 7) * 128;

  const int srow = tid >> 2;
  const u32 sswz = (u32)(((tid & 3) * 16) ^ ((srow & 3) << 4));
  const char* Ag = (const char*)A + (size_t)(m0 + srow) * 2048 + sswz;
  const char* Bg = (const char*)Bt + (size_t)(n0 + srow) * 2048 + sswz;
  const u32 ldsb = (u32)(w * 1024);

#define GSTAGE4(buf, ks_)                                                         \
  do {                                                                            \
    u32 koff_ = (u32)(ks_) * 64;                                                  \
    _Pragma("unroll") for (int p_ = 0; p_ < 2; ++p_) {                            \
      GLD16(Ag + koff_ + (size_t)p_ * 64 * 2048,                                  \
            (char*)A_lds + (buf) * 8192 + p_ * 4096 + ldsb);                      \
      GLD16(Bg + koff_ + (size_t)p_ * 64 * 2048,                                  \
            (char*)B_lds + (buf) * 8192 + p_ * 4096 + ldsb);                      \
    }                                                                             \
  } while (0)

  f32x4 acc[4][4];
#pragma unroll
  for (int i = 0; i < 4; ++i)
#pragma unroll
    for (int j = 0; j < 4; ++j) acc[i][j] = (f32x4){0.f, 0.f, 0.f, 0.f};

  int cur = 0;
  GSTAGE4(0, 0);
  for (int ks = 0; ks < 32; ++ks) {
    GSTAGE4(cur ^ 1, (ks + 1) & 31);
    asm volatile("s_waitcnt vmcnt(4)" ::: "memory");
    __builtin_amdgcn_s_barrier();
    __builtin_amdgcn_sched_barrier(0);
    const char* Ac = (const char*)A_lds + cur * 8192;
    const char* Bc = (const char*)B_lds + cur * 8192;
    bf16x8 af[4], bfr[4];
#pragma unroll
    for (int i = 0; i < 4; ++i) {
      int row = wr * 64 + i * 16 + c;
      af[i] = *(const bf16x8*)(Ac + row * 64 + ((g * 16) ^ ((row & 3) << 4)));
    }
#pragma unroll
    for (int j = 0; j < 4; ++j) {
      int row = wc * 64 + j * 16 + c;
      bfr[j] = *(const bf16x8*)(Bc + row * 64 + ((g * 16) ^ ((row & 3) << 4)));
    }
    __builtin_amdgcn_s_setprio(1);
#pragma unroll
    for (int i = 0; i < 4; ++i)
#pragma unroll
      for (int j = 0; j < 4; ++j)
        acc[i][j] = __builtin_amdgcn_mfma_f32_16x16x32_bf16(af[i], bfr[j], acc[i][j], 0, 0, 0);
    __builtin_amdgcn_s_setprio(0);
    asm volatile("s_waitcnt lgkmcnt(0)" ::: "memory");
    __builtin_amdgcn_s_barrier();
    __builtin_amdgcn_sched_barrier(0);
    cur ^= 1;
  }
#undef GSTAGE4

#pragma unroll
  for (int i = 0; i < 4; ++i)
#pragma unroll
    for (int j = 0; j < 4; ++j)
#pragma unroll
      for (int r = 0; r < 4; ++r) {
        int m = m0 + wr * 64 + i * 16 + g * 4 + r;
        int col = n0 + wc * 64 + j * 16 + c;
        out[(size_t)m * 1024 + col] = acc[i][j][r] + bias[col];
      }
}

// ---------------- fused merge + out-proj (split path): 128x128 tiles ----------------
// A_merged[m][k] = (O0[m][k]+O1[m][k]) / (L0+L1)[head(k)][m], computed during reg-staged
// A staging (issue-early / write-late, round-13-proven skeleton). B via global_load_lds.
// Per k-step in flight at the wait: 2 B-glds + 8 A-loads -> vmcnt(10).
__global__ __launch_bounds__(256) void gemm_out256f(const u16* __restrict__ O0,
                                                    const u16* __restrict__ O1,
                                                    const float* __restrict__ L0,
                                                    const float* __restrict__ L1,
                                                    const u16* __restrict__ Bt,
                                                    float* __restrict__ out,
                                                    const float* __restrict__ bias) {
  __shared__ __align__(16) u16 SH[16384];  // 32KB: A [0,16K) bytes, B [16K,32K) bytes
  u16* A_lds = SH;
  u16* B_lds = SH + 8192;
  const int tid = threadIdx.x;
  const int l = tid & 63, w = tid >> 6;
  const int g = l >> 4, c = l & 15;
  const int wr = w >> 1, wc = w & 1;
  const int flat = blockIdx.x + blockIdx.y * 8;
  const int p = (flat & 7) * 32 + (flat >> 3);
  const int m0 = (p >> 3) * 128, n0 = (p & 7) * 128;

  const int srow = tid >> 2;           // 0..63
  const int chunk = tid & 3;           // 16B chunk within 32-col row
  const int cidx = chunk ^ (srow & 3); // swizzled global chunk (matches read-side XOR)
  const u32 sswz = (u32)(((tid & 3) * 16) ^ ((srow & 3) << 4));
  const char* Bg = (const char*)Bt + (size_t)(n0 + srow) * 2048 + sswz;
  const u32 ldsb = (u32)(w * 1024);

  // A-load registers held across the barrier (issue-early / write-late)
  bf16x8 va, vb, wa, wb;  // O0 row, O0 row+64, O1 row, O1 row+64
  float l0a, l1a, l0b, l1b;

#define A_LOAD(KSN)                                                               \
  {                                                                               \
    int k0n_ = (KSN) * 32, hn_ = (KSN) >> 1;                                      \
    const u16* p0a_ = O0 + (size_t)(m0 + srow) * 1024 + k0n_ + cidx * 8;          \
    const u16* p0b_ = O0 + (size_t)(m0 + srow + 64) * 1024 + k0n_ + cidx * 8;     \
    const u16* p1a_ = O1 + (size_t)(m0 + srow) * 1024 + k0n_ + cidx * 8;          \
    const u16* p1b_ = O1 + (size_t)(m0 + srow + 64) * 1024 + k0n_ + cidx * 8;     \
    va = *(const bf16x8*)(p0a_);                                                  \
    vb = *(const bf16x8*)(p0b_);                                                  \
    wa = *(const bf16x8*)(p1a_);                                                  \
    wb = *(const bf16x8*)(p1b_);                                                  \
    l0a = L0[hn_ * 4096 + m0 + srow];                                             \
    l1a = L1[hn_ * 4096 + m0 + srow];                                             \
    l0b = L0[hn_ * 4096 + m0 + srow + 64];                                        \
    l1b = L1[hn_ * 4096 + m0 + srow + 64];                                        \
  }

#define A_WRITE(BUF)                                                              \
  {                                                                               \
    float inva_ = 1.f / (l0a + l1a);                                              \
    float invb_ = 1.f / (l0b + l1b);                                              \
    uint4 pa_, pb_;                                                               \
    u32 t0_, t1_;                                                                 \
    t0_ = (u32)f2bf((bf2f((u16)va[0]) + bf2f((u16)wa[0])) * inva_);               \
    t1_ = (u32)f2bf((bf2f((u16)va[1]) + bf2f((u16)wa[1])) * inva_);               \
    pa_.x = t0_ | (t1_ << 16);                                                    \
    t0_ = (u32)f2bf((bf2f((u16)va[2]) + bf2f((u16)wa[2])) * inva_);               \
    t1_ = (u32)f2bf((bf2f((u16)va[3]) + bf2f((u16)wa[3])) * inva_);               \
    pa_.y = t0_ | (t1_ << 16);                                                    \
    t0_ = (u32)f2bf((bf2f((u16)va[4]) + bf2f((u16)wa[4])) * inva_);               \
    t1_ = (u32)f2bf((bf2f((u16)va[5]) + bf2f((u16)wa[5])) * inva_);               \
    pa_.z = t0_ | (t1_ << 16);                                                    \
    t0_ = (u32)f2bf((bf2f((u16)va[6]) + bf2f((u16)wa[6])) * inva_);               \
    t1_ = (u32)f2bf((bf2f((u16)va[7]) + bf2f((u16)wa[7])) * inva_);               \
    pa_.w = t0_ | (t1_ << 16);                                                    \
    t0_ = (u32)f2bf((bf2f((u16)vb[0]) + bf2f((u16)wb[0])) * invb_);               \
    t1_ = (u32)f2bf((bf2f((u16)vb[1]) + bf2f((u16)wb[1])) * invb_);               \
    pb_.x = t0_ | (t1_ << 16);                                                    \
    t0_ = (u32)f2bf((bf2f((u16)vb[2]) + bf2f((u16)wb[2])) * invb_);               \
    t1_ = (u32)f2bf((bf2f((u16)vb[3]) + bf2f((u16)wb[3])) * invb_);               \
    pb_.y = t0_ | (t1_ << 16);                                                    \
    t0_ = (u32)f2bf((bf2f((u16)vb[4]) + bf2f((u16)wb[4])) * invb_);               \
    t1_ = (u32)f2bf((bf2f((u16)vb[5]) + bf2f((u16)wb[5])) * invb_);               \
    pb_.z = t0_ | (t1_ << 16);                                                    \
    t0_ = (u32)f2bf((bf2f((u16)vb[6]) + bf2f((u16)wb[6])) * invb_);               \
    t1_ = (u32)f2bf((bf2f((u16)vb[7]) + bf2f((u16)wb[7])) * invb_);               \
    pb_.w = t0_ | (t1_ << 16);                                                    \
    *(uint4*)((char*)A_lds + (BUF) * 8192 + srow * 64 + chunk * 16) = pa_;        \
    *(uint4*)((char*)A_lds + (BUF) * 8192 + 4096 + srow * 64 + chunk * 16) = pb_; \
  }

#define BSTAGE(buf, ks_)                                                          \
  do {                                                                            \
    u32 koff_ = (u32)(ks_) * 64;                                                  \
    _Pragma("unroll") for (int p_ = 0; p_ < 2; ++p_) {                            \
      GLD16(Bg + koff_ + (size_t)p_ * 64 * 2048,                                  \
            (char*)B_lds + (buf) * 8192 + p_ * 4096 + ldsb);                      \
    }                                                                             \
  } while (0)

  f32x4 acc[4][4];
#pragma unroll
  for (int i = 0; i < 4; ++i)
#pragma unroll
    for (int j = 0; j < 4; ++j) acc[i][j] = (f32x4){0.f, 0.f, 0.f, 0.f};

  // prologue: tile 0 (B async; A reg->LDS)
  BSTAGE(0, 0);
  A_LOAD(0);
  A_WRITE(0);

  int cur = 0;
  for (int ks = 0; ks < 32; ++ks) {
    int ksn = (ks + 1) & 31;
    BSTAGE(cur ^ 1, ksn);
    A_LOAD(ksn);  // issue-early: loads land under the MFMA phase
    asm volatile("s_waitcnt vmcnt(10) lgkmcnt(0)" ::: "memory");
    __builtin_amdgcn_s_barrier();
    __builtin_amdgcn_sched_barrier(0);
    const char* Ac = (const char*)A_lds + cur * 8192;
    const char* Bc = (const char*)B_lds + cur * 8192;
    bf16x8 af[4], bfr[4];
#pragma unroll
    for (int i = 0; i < 4; ++i) {
      int row = wr * 64 + i * 16 + c;
      af[i] = *(const bf16x8*)(Ac + row * 64 + ((g * 16) ^ ((row & 3) << 4)));
    }
#pragma unroll
    for (int j = 0; j < 4; ++j) {
      int row = wc * 64 + j * 16 + c;
      bfr[j] = *(const bf16x8*)(Bc + row * 64 + ((g * 16) ^ ((row & 3) << 4)));
    }
    __builtin_amdgcn_s_setprio(1);
#pragma unroll
    for (int i = 0; i < 4; ++i)
#pragma unroll
      for (int j = 0; j < 4; ++j)
        acc[i][j] = __builtin_amdgcn_mfma_f32_16x16x32_bf16(af[i], bfr[j], acc[i][j], 0, 0, 0);
    __builtin_amdgcn_s_setprio(0);
    A_WRITE(cur ^ 1);  // write-late: merge/normalize/cvt + 2x ds_write_b128
    asm volatile("s_waitcnt lgkmcnt(0)" ::: "memory");
    __builtin_amdgcn_s_barrier();
    __builtin_amdgcn_sched_barrier(0);
    cur ^= 1;
  }
#undef A_LOAD
#undef A_WRITE
#undef BSTAGE

#pragma unroll
  for (int i = 0; i < 4; ++i)
#pragma unroll
    for (int j = 0; j < 4; ++j)
#pragma unroll
      for (int r = 0; r < 4; ++r) {
        int m = m0 + wr * 64 + i * 16 + g * 4 + r;
        int col = n0 + wc * 64 + j * 16 + c;
        out[(size_t)m * 1024 + col] = acc[i][j][r] + bias[col];
      }
}

// ---------------- flash attention, swapped-QK^T 32x32, no-max exp2 softmax ----------------
// ROUND-10-EXACT structure (proven): double-buffered K/V, TWO barriers per KV tile
// (vmcnt(4)+barrier pre-compute; lgkmcnt(0)+barrier post-compute). 64 q-rows per wave.
// Split path writes bf16 (unnormalized) partials.
template <int SPLIT>
__global__ __launch_bounds__(256, 2) void flash_attn_t(const u16* __restrict__ Qb,
                                                       const u16* __restrict__ Kb,
                                                       const u16* __restrict__ Vt,
                                                       u16* __restrict__ Ob,
                                                       u16* __restrict__ Op,
                                                       float* __restrict__ Lp) {
  constexpr int NT = SPLIT ? 32 : 64;  // KV tiles per block
  __shared__ __align__(16) u16 K_lds[2][64 * 64];
  __shared__ __align__(16) u16 V_lds[2][64 * 64];
  const int tid = threadIdx.x;
  const int l = tid & 63, w = tid >> 6;
  const int lq = l & 31, hi = l >> 5;
  const int h = blockIdx.y;
  const int z = SPLIT ? blockIdx.z : 0;
  const int kb = z * 32;                      // KV tile base (split half)
  const int qb = blockIdx.x * 256 + w * 64;   // wave's 64-row q base
  const int q0 = qb + lq, q1 = qb + 32 + lq;

  bf16x8 qf0[4], qf1[4];
  {
    const u16* qr0 = Qb + (size_t)q0 * 1024 + h * 64;
    const u16* qr1 = Qb + (size_t)q1 * 1024 + h * 64;
#pragma unroll
    for (int dm = 0; dm < 4; ++dm) {
      qf0[dm] = *(const bf16x8*)(qr0 + dm * 16 + hi * 8);
      qf1[dm] = *(const bf16x8*)(qr1 + dm * 16 + hi * 8);
    }
  }

  f32x16 ot0[2], ot1[2];
#pragma unroll
  for (int a = 0; a < 2; ++a)
#pragma unroll
    for (int r = 0; r < 16; ++r) { ot0[a][r] = 0.f; ot1[a][r] = 0.f; }
  float lrow0 = 0.f, lrow1 = 0.f;
  u32 pkA0[16], pkA1[16], pkB0[16], pkB1[16];

  const int srow = tid >> 3;
  const u32 sswz = (u32)(((tid & 7) * 16) ^ ((srow & 7) << 4));
  const char* Kg = (const char*)Kb + ((size_t)srow * 1024 + h * 64) * 2 + sswz;
  const char* Vg = (const char*)Vt + ((size_t)(h * 64 + srow) * 4096) * 2 + sswz;
  const u32 ldsb = (u32)(w * 1024);

  // PV only: each V fragment read once, feeds both q-groups' accumulators
#define PVONLY(P0, P1, VSLOT)                                                     \
  {                                                                               \
    const char* Vp_ = (const char*)(VSLOT);                                       \
    __builtin_amdgcn_s_setprio(1);                                                \
    _Pragma("unroll") for (int sti_ = 0; sti_ < 4; ++sti_) {                      \
      u32x4 pw0_ = {P0[sti_ * 4 + 0], P0[sti_ * 4 + 1], P0[sti_ * 4 + 2],         \
                    P0[sti_ * 4 + 3]};                                            \
      u32x4 pw1_ = {P1[sti_ * 4 + 0], P1[sti_ * 4 + 1], P1[sti_ * 4 + 2],         \
                    P1[sti_ * 4 + 3]};                                            \
      bf16x8 pf0_ = __builtin_bit_cast(bf16x8, pw0_);                             \
      bf16x8 pf1_ = __builtin_bit_cast(bf16x8, pw1_);                             \
      const u32 cb_ = (u32)(sti_ * 32 + hi * 16);                                 \
      _Pragma("unroll") for (int a_ = 0; a_ < 2; ++a_) {                          \
        const int rowd_ = a_ * 32 + lq;                                           \
        const u32 rs_ = (u32)(rowd_ * 128), rz_ = (u32)((rowd_ & 7) << 4);        \
        bf16x8 vf_ = *(const bf16x8*)(Vp_ + rs_ + (cb_ ^ rz_));                   \
        ot0[a_] = __builtin_amdgcn_mfma_f32_32x32x16_bf16(vf_, pf0_, ot0[a_], 0, 0, 0); \
        ot1[a_] = __builtin_amdgcn_mfma_f32_32x32x16_bf16(vf_, pf1_, ot1[a_], 0, 0, 0); \
      }                                                                           \
    }                                                                             \
    __builtin_amdgcn_s_setprio(0);                                                \
  }

  // BODY: stage K(TI+1),V(TI); QK(TI) both groups (kf shared); PV(TI-1); softmax->pk
#define BODY(TI, C0, C1, P0, P1, DOPREV)                                          \
  {                                                                               \
    const int ti_ = (TI);                                                         \
    const int nxt_ = (ti_ + 1) & (NT - 1);                                        \
    {                                                                             \
      const char* kg_ = Kg + (size_t)(kb + nxt_) * 64 * 2048;                     \
      char* kl_ = (char*)K_lds[nxt_ & 1] + ldsb;                                  \
      GLD16(kg_, kl_);                                                            \
      GLD16(kg_ + 32 * 2048, kl_ + 4096);                                         \
      const char* vg_ = Vg + (size_t)(kb + ti_) * 128;                            \
      char* vl_ = (char*)V_lds[ti_ & 1] + ldsb;                                   \
      GLD16(vg_, vl_);                                                            \
      GLD16(vg_ + (size_t)32 * 8192, vl_ + 4096);                                 \
    }                                                                             \
    asm volatile("s_waitcnt vmcnt(4)" ::: "memory");                              \
    __builtin_amdgcn_s_barrier();                                                 \
    __builtin_amdgcn_sched_barrier(0);                                            \
    const char* Kc_ = (const char*)K_lds[ti_ & 1];                                \
    f32x16 st0_[2], st1_[2];                                                      \
    _Pragma("unroll") for (int s_ = 0; s_ < 2; ++s_)                              \
    _Pragma("unroll") for (int r_ = 0; r_ < 16; ++r_) {                           \
      st0_[s_][r_] = 0.f;                                                         \
      st1_[s_][r_] = 0.f;                                                         \
    }                                                                             \
    __builtin_amdgcn_s_setprio(1);                                                \
    _Pragma("unroll") for (int s_ = 0; s_ < 2; ++s_) {                            \
      const int row_ = s_ * 32 + lq;                                              \
      const u32 rs_ = (u32)(row_ * 128), rz_ = (u32)((row_ & 7) << 4);            \
      _Pragma("unroll") for (int dm_ = 0; dm_ < 4; ++dm_) {                       \
        bf16x8 kf_ = *(const bf16x8*)(Kc_ + rs_ + ((u32)(dm_ * 32 + hi * 16) ^ rz_)); \
        st0_[s_] = __builtin_amdgcn_mfma_f32_32x32x16_bf16(kf_, qf0[dm_], st0_[s_], 0, 0, 0); \
        st1_[s_] = __builtin_amdgcn_mfma_f32_32x32x16_bf16(kf_, qf1[dm_], st1_[s_], 0, 0, 0); \
      }                                                                           \
    }                                                                             \
    __builtin_amdgcn_s_setprio(0);                                                \
    if (DOPREV) PVONLY(P0, P1, V_lds[(ti_ - 1) & 1]);                             \
    float rs0_ = 0.f, rs1_ = 0.f;                                                 \
    _Pragma("unroll") for (int s_ = 0; s_ < 2; ++s_)                              \
    _Pragma("unroll") for (int j_ = 0; j_ < 8; ++j_) {                            \
      float a0_ = __builtin_amdgcn_exp2f(st0_[s_][2 * j_]);                       \
      float a1_ = __builtin_amdgcn_exp2f(st0_[s_][2 * j_ + 1]);                   \
      rs0_ += a0_ + a1_;                                                          \
      u32 wp0_;                                                                   \
      asm("v_cvt_pk_bf16_f32 %0, %1, %2" : "=v"(wp0_) : "v"(a0_), "v"(a1_));      \
      C0[s_ * 8 + j_] = wp0_;                                                     \
      float b0_ = __builtin_amdgcn_exp2f(st1_[s_][2 * j_]);                       \
      float b1_ = __builtin_amdgcn_exp2f(st1_[s_][2 * j_ + 1]);                   \
      rs1_ += b0_ + b1_;                                                          \
      u32 wp1_;                                                                   \
      asm("v_cvt_pk_bf16_f32 %0, %1, %2" : "=v"(wp1_) : "v"(b0_), "v"(b1_));      \
      C1[s_ * 8 + j_] = wp1_;                                                     \
    }                                                                             \
    lrow0 += rs0_;                                                                \
    lrow1 += rs1_;                                                                \
    asm volatile("s_waitcnt lgkmcnt(0)" ::: "memory");                            \
    __builtin_amdgcn_s_barrier();                                                 \
    __builtin_amdgcn_sched_barrier(0);                                            \
  }

  {  // prologue: stage K(kb)
    const char* kg0 = Kg + (size_t)kb * 64 * 2048;
    char* kl = (char*)K_lds[0] + ldsb;
    GLD16(kg0, kl);
    GLD16(kg0 + 32 * 2048, kl + 4096);
  }

  BODY(0, pkA0, pkA1, pkA0, pkA1, 0);
  for (int i = 1; i < NT - 1; i += 2) {
    BODY(i, pkB0, pkB1, pkA0, pkA1, 1);
    BODY(i + 1, pkA0, pkA1, pkB0, pkB1, 1);
  }
  BODY(NT - 1, pkB0, pkB1, pkA0, pkA1, 1);
  asm volatile("s_waitcnt vmcnt(0)" ::: "memory");
  __builtin_amdgcn_s_barrier();
  __builtin_amdgcn_sched_barrier(0);
  PVONLY(pkB0, pkB1, V_lds[(NT - 1) & 1]);

#undef BODY
#undef PVONLY

  lrow0 += __shfl_xor(lrow0, 32, 64);
  lrow1 += __shfl_xor(lrow1, 32, 64);
  if constexpr (SPLIT) {
    // bf16 unnormalized partials; z-stride = 4096*1024 u16 elements (8 MB)
    u16* or0 = Op + (size_t)z * (4096 * 1024) + (size_t)q0 * 1024 + h * 64 + hi * 4;
    u16* or1 = Op + (size_t)z * (4096 * 1024) + (size_t)q1 * 1024 + h * 64 + hi * 4;
#pragma unroll
    for (int a = 0; a < 2; ++a)
#pragma unroll
      for (int rr = 0; rr < 4; ++rr) {
        ushort4 o4;
        o4.x = f2bf(ot0[a][rr * 4 + 0]);
        o4.y = f2bf(ot0[a][rr * 4 + 1]);
        o4.z = f2bf(ot0[a][rr * 4 + 2]);
        o4.w = f2bf(ot0[a][rr * 4 + 3]);
        *(ushort4*)(or0 + a * 32 + rr * 8) = o4;
        o4.x = f2bf(ot1[a][rr * 4 + 0]);
        o4.y = f2bf(ot1[a][rr * 4 + 1]);
        o4.z = f2bf(ot1[a][rr * 4 + 2]);
        o4.w = f2bf(ot1[a][rr * 4 + 3]);
        *(ushort4*)(or1 + a * 32 + rr * 8) = o4;
      }
    if (hi == 0) {
      Lp[z * 65536 + h * 4096 + q0] = lrow0;
      Lp[z * 65536 + h * 4096 + q1] = lrow1;
    }
  } else {
    float inv0 = 1.f / lrow0, inv1 = 1.f / lrow1;
    u16* or0 = Ob + (size_t)q0 * 1024 + h * 64 + hi * 4;
    u16* or1 = Ob + (size_t)q1 * 1024 + h * 64 + hi * 4;
#pragma unroll
    for (int a = 0; a < 2; ++a)
#pragma unroll
      for (int rr = 0; rr < 4; ++rr) {
        ushort4 o4;
        o4.x = f2bf(ot0[a][rr * 4 + 0] * inv0);
        o4.y = f2bf(ot0[a][rr * 4 + 1] * inv0);
        o4.z = f2bf(ot0[a][rr * 4 + 2] * inv0);
        o4.w = f2bf(ot0[a][rr * 4 + 3] * inv0);
        *(ushort4*)(or0 + a * 32 + rr * 8) = o4;
        o4.x = f2bf(ot1[a][rr * 4 + 0] * inv1);
        o4.y = f2bf(ot1[a][rr * 4 + 1] * inv1);
        o4.z = f2bf(ot1[a][rr * 4 + 2] * inv1);
        o4.w = f2bf(ot1[a][rr * 4 + 3] * inv1);
        *(ushort4*)(or1 + a * 32 + rr * 8) = o4;
      }
  }
}

extern "C" void kernel_launch(void* const* d_in, const int* in_sizes, int n_in,
                              void* d_out, int out_size, void* d_ws, size_t ws_size,
                              hipStream_t stream) {
  const float* x = (const float*)d_in[0];
  const float* Wq = (const float*)d_in[1];
  const float* Wk = (const float*)d_in[2];
  const float* Wv = (const float*)d_in[3];
  const float* Wo = (const float*)d_in[4];
  const float* bo = (const float*)d_in[5];
  float* out = (float*)d_out;

  char* ws = (char*)d_ws;
  u16* xb  = (u16*)(ws);                  // 8 MB (dead after gemm_qkv)
  u16* Wqt = (u16*)(ws + (8u << 20));     // 2 MB  [Wqt|Wkt|Wvt] contiguous
  u16* Wot = (u16*)(ws + (14u << 20));    // 2 MB
  u16* Qb  = (u16*)(ws + (16u << 20));    // 8 MB
  u16* Kbf = (u16*)(ws + (24u << 20));    // 8 MB
  u16* Vth = (u16*)(ws + (32u << 20));    // 8 MB  [h][64][n] (quad-interleaved n)
  u16* Ob  = (u16*)(ws + (40u << 20));    // 8 MB (fallback path output)
  u16* Op  = (u16*)(ws + (40u << 20));    // 16 MB (split path: 2x bf16 partials, 8 MB each)
  float* Lp = (float*)(ws + (56u << 20)); // 512 KB (2x16x4096 f32)
  u16* Wkt = Wqt + (1u << 20);
  u16* Wvt = Wqt + (2u << 20);

  const bool split = ws_size >= ((56u << 20) + (1u << 19));

  prep<<<dim3(16, 16, 6), 256, 0, stream>>>(x, Wq, Wk, Wv, Wo, xb, Wqt, Wkt, Wvt, Wot);
  gemm_qkv<<<dim3(24, 32), 256, 0, stream>>>(xb, Wqt, Qb, Kbf, Vth);

  if (split) {
    flash_attn_t<1><<<dim3(16, 16, 2), 256, 0, stream>>>(Qb, Kbf, Vth, nullptr, Op, Lp);
    gemm_out256f<<<dim3(8, 32), 256, 0, stream>>>(Op, Op + (1u << 22), Lp, Lp + 65536,
                                                  Wot, out, bo);
  } else {
    flash_attn_t<0><<<dim3(16, 16, 1), 256, 0, stream>>>(Qb, Kbf, Vth, Ob, nullptr, nullptr);
    gemm_out256<<<dim3(8, 32), 256, 0, stream>>>(Ob, Wot, out, bo);
  }
}

// Round 19
// 157.592 us; speedup vs baseline: 1.0594x; 1.0594x over previous
//
#include <hip/hip_runtime.h>
#include <stdint.h>

#define NH 16
#define NN 4096

typedef __attribute__((ext_vector_type(8))) short bf16x8;
typedef __attribute__((ext_vector_type(4))) short bf16x4;
typedef __attribute__((ext_vector_type(4))) float f32x4;
typedef __attribute__((ext_vector_type(16))) float f32x16;
typedef unsigned short u16;
typedef unsigned int u32;
typedef __attribute__((ext_vector_type(4))) u32 u32x4;

__device__ __forceinline__ u16 f2bf(float f) {
  u32 u = __float_as_uint(f);
  return (u16)((u + 0x7FFFu + ((u >> 16) & 1u)) >> 16);
}
__device__ __forceinline__ float bf2f(u16 v) {
  return __uint_as_float(((u32)v) << 16);
}

#define GLD16(gp, lp)                                              \
  __builtin_amdgcn_global_load_lds(                                \
      (__attribute__((address_space(1))) void*)(gp),               \
      (__attribute__((address_space(3))) void*)(lp), 16, 0, 0)

// ---------------- prep: fused weight transposes (z<4) + x f32->bf16 (z=4,5) ----------------
__global__ __launch_bounds__(256) void prep(const float* __restrict__ x,
                                            const float* __restrict__ Wq,
                                            const float* __restrict__ Wk,
                                            const float* __restrict__ Wv,
                                            const float* __restrict__ Wo,
                                            u16* __restrict__ xb,
                                            u16* __restrict__ Wqt, u16* __restrict__ Wkt,
                                            u16* __restrict__ Wvt, u16* __restrict__ Wot) {
  __shared__ float tile[64][65];
  int z = blockIdx.z;
  int tid = threadIdx.x;
  if (z >= 4) {
    int bi = (z - 4) * 256 + blockIdx.y * 16 + blockIdx.x;
    size_t base = (size_t)bi * 8192;
#pragma unroll
    for (int k = 0; k < 4; ++k) {
      size_t i = base + (size_t)k * 2048 + tid * 8;
      float4 a = *(const float4*)(x + i);
      float4 b = *(const float4*)(x + i + 4);
      uint4 o;
      o.x = (u32)f2bf(a.x) | ((u32)f2bf(a.y) << 16);
      o.y = (u32)f2bf(a.z) | ((u32)f2bf(a.w) << 16);
      o.z = (u32)f2bf(b.x) | ((u32)f2bf(b.y) << 16);
      o.w = (u32)f2bf(b.z) | ((u32)f2bf(b.w) << 16);
      *(uint4*)(xb + i) = o;
    }
    return;
  }
  const float* src;
  u16* dst;
  float scale = 1.0f;
  if (z == 0) { src = Wq; dst = Wqt; scale = 0.125f * 1.4426950408889634f; }
  else if (z == 1) { src = Wk; dst = Wkt; }
  else if (z == 2) { src = Wv; dst = Wvt; }
  else { src = Wo; dst = Wot; }
  int tx = tid & 63, ty = tid >> 6;
  int c0 = blockIdx.x * 64, r0 = blockIdx.y * 64;
#pragma unroll
  for (int i = ty; i < 64; i += 4)
    tile[i][tx] = src[(size_t)(r0 + i) * 1024 + c0 + tx];
  __syncthreads();
#pragma unroll
  for (int i = ty; i < 64; i += 4)
    dst[(size_t)(c0 + i) * 1024 + r0 + tx] = f2bf(tile[tx][i] * scale);
}

// ---------------- fused QKV GEMM: [4096][1024] @ Wt[3072][1024]^T ----------------
// Bijective XCD swizzle (768 blocks = 8 x 96). V (sec==2): acc -> swizzled LDS tile ->
// coalesced V^T stores (quad-interleaved n).
__global__ __launch_bounds__(256) void gemm_qkv(const u16* __restrict__ A,
                                                const u16* __restrict__ Bt,
                                                u16* __restrict__ Qb, u16* __restrict__ Kb,
                                                u16* __restrict__ Vth) {
  __shared__ __align__(16) u16 SH[16384];  // 32KB
  u16* A_lds = SH;
  u16* B_lds = SH + 8192;
  const int tid = threadIdx.x;
  const int l = tid & 63, w = tid >> 6;
  const int g = l >> 4, c = l & 15;
  const int wr = w >> 1, wc = w & 1;
  const int flat = blockIdx.x + blockIdx.y * 24;
  const int p = (flat & 7) * 96 + (flat >> 3);
  const int m0 = (p / 24) * 128, n0 = (p % 24) * 128;

  const int srow = tid >> 2;
  const u32 sswz = (u32)(((tid & 3) * 16) ^ ((srow & 3) << 4));
  const char* Ag = (const char*)A + (size_t)(m0 + srow) * 2048 + sswz;
  const char* Bg = (const char*)Bt + (size_t)(n0 + srow) * 2048 + sswz;
  const u32 ldsb = (u32)(w * 1024);

#define GSTAGE(buf, ks_)                                                          \
  do {                                                                            \
    u32 koff_ = (u32)(ks_) * 64;                                                  \
    _Pragma("unroll") for (int p_ = 0; p_ < 2; ++p_) {                            \
      GLD16(Ag + koff_ + (size_t)p_ * 64 * 2048,                                  \
            (char*)A_lds + (buf) * 8192 + p_ * 4096 + ldsb);                      \
      GLD16(Bg + koff_ + (size_t)p_ * 64 * 2048,                                  \
            (char*)B_lds + (buf) * 8192 + p_ * 4096 + ldsb);                      \
    }                                                                             \
  } while (0)

  f32x4 acc[4][4];
#pragma unroll
  for (int i = 0; i < 4; ++i)
#pragma unroll
    for (int j = 0; j < 4; ++j) acc[i][j] = (f32x4){0.f, 0.f, 0.f, 0.f};

  int cur = 0;
  GSTAGE(0, 0);
  for (int ks = 0; ks < 32; ++ks) {
    GSTAGE(cur ^ 1, (ks + 1) & 31);
    asm volatile("s_waitcnt vmcnt(4)" ::: "memory");
    __builtin_amdgcn_s_barrier();
    __builtin_amdgcn_sched_barrier(0);
    const char* Ac = (const char*)A_lds + cur * 8192;
    const char* Bc = (const char*)B_lds + cur * 8192;
    bf16x8 af[4], bfr[4];
#pragma unroll
    for (int i = 0; i < 4; ++i) {
      int row = wr * 64 + i * 16 + c;
      af[i] = *(const bf16x8*)(Ac + row * 64 + ((g * 16) ^ ((row & 3) << 4)));
    }
#pragma unroll
    for (int j = 0; j < 4; ++j) {
      int row = wc * 64 + j * 16 + c;
      bfr[j] = *(const bf16x8*)(Bc + row * 64 + ((g * 16) ^ ((row & 3) << 4)));
    }
    __builtin_amdgcn_s_setprio(1);
#pragma unroll
    for (int i = 0; i < 4; ++i)
#pragma unroll
      for (int j = 0; j < 4; ++j)
        acc[i][j] = __builtin_amdgcn_mfma_f32_16x16x32_bf16(af[i], bfr[j], acc[i][j], 0, 0, 0);
    __builtin_amdgcn_s_setprio(0);
    asm volatile("s_waitcnt lgkmcnt(0)" ::: "memory");
    __builtin_amdgcn_s_barrier();
    __builtin_amdgcn_sched_barrier(0);
    cur ^= 1;
  }
#undef GSTAGE

  const int sec = n0 >> 10;  // block-uniform: 0=Q, 1=K, 2=V
  if (sec < 2) {
#pragma unroll
    for (int i = 0; i < 4; ++i)
#pragma unroll
      for (int j = 0; j < 4; ++j)
#pragma unroll
        for (int r = 0; r < 4; ++r) {
          int m = m0 + wr * 64 + i * 16 + g * 4 + r;
          int cc = (n0 + wc * 64 + j * 16 + c) & 1023;
          u16 v = f2bf(acc[i][j][r]);
          if (sec == 0) Qb[(size_t)m * 1024 + cc] = v;
          else Kb[(size_t)m * 1024 + cc] = v;
        }
  } else {
    // V^T via LDS transpose (loop's final barrier already synced; SH is free).
    const int gq = ((g & 1) << 1) | (g >> 1);  // quad-swap 1<->2 for V n-order
    const int cc0 = n0 & 1023;
#pragma unroll
    for (int i = 0; i < 4; ++i)
#pragma unroll
      for (int j = 0; j < 4; ++j)
#pragma unroll
        for (int r = 0; r < 4; ++r) {
          int cl = wc * 64 + j * 16 + c;            // local col (d)
          int mql = wr * 64 + i * 16 + gq * 4 + r;  // local n, quad-interleaved
          SH[cl * 128 + (mql ^ ((cl & 15) << 3))] = f2bf(acc[i][j][r]);
        }
    __syncthreads();
#pragma unroll
    for (int p2 = 0; p2 < 4; ++p2) {
      int row = p2 * 32 + (tid >> 3);
#pragma unroll
      for (int half = 0; half < 2; ++half) {
        int mq = (tid & 7) * 8 + half * 64;
        bf16x8 vv = *(const bf16x8*)&SH[row * 128 + (mq ^ ((row & 15) << 3))];
        *(bf16x8*)(Vth + (size_t)(cc0 + row) * 4096 + m0 + mq) = vv;
      }
    }
  }
}

// ---------------- out-proj GEMM, 128x128 tiles (gemm_qkv-clone loop, f32+bias epilogue) ----
// Grid 8 x 32 = 256 blocks; bijective XCD swizzle (256 = 8 x 32).
__global__ __launch_bounds__(256) void gemm_out256(const u16* __restrict__ A,
                                                   const u16* __restrict__ Bt,
                                                   float* __restrict__ out,
                                                   const float* __restrict__ bias) {
  __shared__ __align__(16) u16 SH[16384];  // 32KB
  u16* A_lds = SH;
  u16* B_lds = SH + 8192;
  const int tid = threadIdx.x;
  const int l = tid & 63, w = tid >> 6;
  const int g = l >> 4, c = l & 15;
  const int wr = w >> 1, wc = w & 1;
  // XCD swizzle: flat = bx + by*8; p = (flat%8)*32 + flat/8; n-block = p%8, m-block = p/8.
  const int flat = blockIdx.x + blockIdx.y * 8;
  const int p = (flat & 7) * 32 + (flat >> 3);
  const int m0 = (p >> 3) * 128, n0 = (p & 7) * 128;

  const int srow = tid >> 2;
  const u32 sswz = (u32)(((tid & 3) * 16) ^ ((srow & 3) << 4));
  const char* Ag = (const char*)A + (size_t)(m0 + srow) * 2048 + sswz;
  const char* Bg = (const char*)Bt + (size_t)(n0 + srow) * 2048 + sswz;
  const u32 ldsb = (u32)(w * 1024);

#define GSTAGE4(buf, ks_)                                                         \
  do {                                                                            \
    u32 koff_ = (u32)(ks_) * 64;                                                  \
    _Pragma("unroll") for (int p_ = 0; p_ < 2; ++p_) {                            \
      GLD16(Ag + koff_ + (size_t)p_ * 64 * 2048,                                  \
            (char*)A_lds + (buf) * 8192 + p_ * 4096 + ldsb);                      \
      GLD16(Bg + koff_ + (size_t)p_ * 64 * 2048,                                  \
            (char*)B_lds + (buf) * 8192 + p_ * 4096 + ldsb);                      \
    }                                                                             \
  } while (0)

  f32x4 acc[4][4];
#pragma unroll
  for (int i = 0; i < 4; ++i)
#pragma unroll
    for (int j = 0; j < 4; ++j) acc[i][j] = (f32x4){0.f, 0.f, 0.f, 0.f};

  int cur = 0;
  GSTAGE4(0, 0);
  for (int ks = 0; ks < 32; ++ks) {
    GSTAGE4(cur ^ 1, (ks + 1) & 31);
    asm volatile("s_waitcnt vmcnt(4)" ::: "memory");
    __builtin_amdgcn_s_barrier();
    __builtin_amdgcn_sched_barrier(0);
    const char* Ac = (const char*)A_lds + cur * 8192;
    const char* Bc = (const char*)B_lds + cur * 8192;
    bf16x8 af[4], bfr[4];
#pragma unroll
    for (int i = 0; i < 4; ++i) {
      int row = wr * 64 + i * 16 + c;
      af[i] = *(const bf16x8*)(Ac + row * 64 + ((g * 16) ^ ((row & 3) << 4)));
    }
#pragma unroll
    for (int j = 0; j < 4; ++j) {
      int row = wc * 64 + j * 16 + c;
      bfr[j] = *(const bf16x8*)(Bc + row * 64 + ((g * 16) ^ ((row & 3) << 4)));
    }
    __builtin_amdgcn_s_setprio(1);
#pragma unroll
    for (int i = 0; i < 4; ++i)
#pragma unroll
      for (int j = 0; j < 4; ++j)
        acc[i][j] = __builtin_amdgcn_mfma_f32_16x16x32_bf16(af[i], bfr[j], acc[i][j], 0, 0, 0);
    __builtin_amdgcn_s_setprio(0);
    asm volatile("s_waitcnt lgkmcnt(0)" ::: "memory");
    __builtin_amdgcn_s_barrier();
    __builtin_amdgcn_sched_barrier(0);
    cur ^= 1;
  }
#undef GSTAGE4

#pragma unroll
  for (int i = 0; i < 4; ++i)
#pragma unroll
    for (int j = 0; j < 4; ++j)
#pragma unroll
      for (int r = 0; r < 4; ++r) {
        int m = m0 + wr * 64 + i * 16 + g * 4 + r;
        int col = n0 + wc * 64 + j * 16 + c;
        out[(size_t)m * 1024 + col] = acc[i][j][r] + bias[col];
      }
}

// ---------------- flash attention, swapped-QK^T 32x32, no-max exp2 softmax ----------------
// ROUND-10-EXACT structure (proven): double-buffered K/V, TWO barriers per KV tile
// (vmcnt(4)+barrier pre-compute; lgkmcnt(0)+barrier post-compute). 64 q-rows per wave.
// Split path writes bf16 (unnormalized) partials.
template <int SPLIT>
__global__ __launch_bounds__(256, 2) void flash_attn_t(const u16* __restrict__ Qb,
                                                       const u16* __restrict__ Kb,
                                                       const u16* __restrict__ Vt,
                                                       u16* __restrict__ Ob,
                                                       u16* __restrict__ Op,
                                                       float* __restrict__ Lp) {
  constexpr int NT = SPLIT ? 32 : 64;  // KV tiles per block
  __shared__ __align__(16) u16 K_lds[2][64 * 64];
  __shared__ __align__(16) u16 V_lds[2][64 * 64];
  const int tid = threadIdx.x;
  const int l = tid & 63, w = tid >> 6;
  const int lq = l & 31, hi = l >> 5;
  const int h = blockIdx.y;
  const int z = SPLIT ? blockIdx.z : 0;
  const int kb = z * 32;                      // KV tile base (split half)
  const int qb = blockIdx.x * 256 + w * 64;   // wave's 64-row q base
  const int q0 = qb + lq, q1 = qb + 32 + lq;

  bf16x8 qf0[4], qf1[4];
  {
    const u16* qr0 = Qb + (size_t)q0 * 1024 + h * 64;
    const u16* qr1 = Qb + (size_t)q1 * 1024 + h * 64;
#pragma unroll
    for (int dm = 0; dm < 4; ++dm) {
      qf0[dm] = *(const bf16x8*)(qr0 + dm * 16 + hi * 8);
      qf1[dm] = *(const bf16x8*)(qr1 + dm * 16 + hi * 8);
    }
  }

  f32x16 ot0[2], ot1[2];
#pragma unroll
  for (int a = 0; a < 2; ++a)
#pragma unroll
    for (int r = 0; r < 16; ++r) { ot0[a][r] = 0.f; ot1[a][r] = 0.f; }
  float lrow0 = 0.f, lrow1 = 0.f;
  u32 pkA0[16], pkA1[16], pkB0[16], pkB1[16];

  const int srow = tid >> 3;
  const u32 sswz = (u32)(((tid & 7) * 16) ^ ((srow & 7) << 4));
  const char* Kg = (const char*)Kb + ((size_t)srow * 1024 + h * 64) * 2 + sswz;
  const char* Vg = (const char*)Vt + ((size_t)(h * 64 + srow) * 4096) * 2 + sswz;
  const u32 ldsb = (u32)(w * 1024);

  // PV only: each V fragment read once, feeds both q-groups' accumulators
#define PVONLY(P0, P1, VSLOT)                                                     \
  {                                                                               \
    const char* Vp_ = (const char*)(VSLOT);                                       \
    __builtin_amdgcn_s_setprio(1);                                                \
    _Pragma("unroll") for (int sti_ = 0; sti_ < 4; ++sti_) {                      \
      u32x4 pw0_ = {P0[sti_ * 4 + 0], P0[sti_ * 4 + 1], P0[sti_ * 4 + 2],         \
                    P0[sti_ * 4 + 3]};                                            \
      u32x4 pw1_ = {P1[sti_ * 4 + 0], P1[sti_ * 4 + 1], P1[sti_ * 4 + 2],         \
                    P1[sti_ * 4 + 3]};                                            \
      bf16x8 pf0_ = __builtin_bit_cast(bf16x8, pw0_);                             \
      bf16x8 pf1_ = __builtin_bit_cast(bf16x8, pw1_);                             \
      const u32 cb_ = (u32)(sti_ * 32 + hi * 16);                                 \
      _Pragma("unroll") for (int a_ = 0; a_ < 2; ++a_) {                          \
        const int rowd_ = a_ * 32 + lq;                                           \
        const u32 rs_ = (u32)(rowd_ * 128), rz_ = (u32)((rowd_ & 7) << 4);        \
        bf16x8 vf_ = *(const bf16x8*)(Vp_ + rs_ + (cb_ ^ rz_));                   \
        ot0[a_] = __builtin_amdgcn_mfma_f32_32x32x16_bf16(vf_, pf0_, ot0[a_], 0, 0, 0); \
        ot1[a_] = __builtin_amdgcn_mfma_f32_32x32x16_bf16(vf_, pf1_, ot1[a_], 0, 0, 0); \
      }                                                                           \
    }                                                                             \
    __builtin_amdgcn_s_setprio(0);                                                \
  }

  // BODY: stage K(TI+1),V(TI); QK(TI) both groups (kf shared); PV(TI-1); softmax->pk
#define BODY(TI, C0, C1, P0, P1, DOPREV)                                          \
  {                                                                               \
    const int ti_ = (TI);                                                         \
    const int nxt_ = (ti_ + 1) & (NT - 1);                                        \
    {                                                                             \
      const char* kg_ = Kg + (size_t)(kb + nxt_) * 64 * 2048;                     \
      char* kl_ = (char*)K_lds[nxt_ & 1] + ldsb;                                  \
      GLD16(kg_, kl_);                                                            \
      GLD16(kg_ + 32 * 2048, kl_ + 4096);                                         \
      const char* vg_ = Vg + (size_t)(kb + ti_) * 128;                            \
      char* vl_ = (char*)V_lds[ti_ & 1] + ldsb;                                   \
      GLD16(vg_, vl_);                                                            \
      GLD16(vg_ + (size_t)32 * 8192, vl_ + 4096);                                 \
    }                                                                             \
    asm volatile("s_waitcnt vmcnt(4)" ::: "memory");                              \
    __builtin_amdgcn_s_barrier();                                                 \
    __builtin_amdgcn_sched_barrier(0);                                            \
    const char* Kc_ = (const char*)K_lds[ti_ & 1];                                \
    f32x16 st0_[2], st1_[2];                                                      \
    _Pragma("unroll") for (int s_ = 0; s_ < 2; ++s_)                              \
    _Pragma("unroll") for (int r_ = 0; r_ < 16; ++r_) {                           \
      st0_[s_][r_] = 0.f;                                                         \
      st1_[s_][r_] = 0.f;                                                         \
    }                                                                             \
    __builtin_amdgcn_s_setprio(1);                                                \
    _Pragma("unroll") for (int s_ = 0; s_ < 2; ++s_) {                            \
      const int row_ = s_ * 32 + lq;                                              \
      const u32 rs_ = (u32)(row_ * 128), rz_ = (u32)((row_ & 7) << 4);            \
      _Pragma("unroll") for (int dm_ = 0; dm_ < 4; ++dm_) {                       \
        bf16x8 kf_ = *(const bf16x8*)(Kc_ + rs_ + ((u32)(dm_ * 32 + hi * 16) ^ rz_)); \
        st0_[s_] = __builtin_amdgcn_mfma_f32_32x32x16_bf16(kf_, qf0[dm_], st0_[s_], 0, 0, 0); \
        st1_[s_] = __builtin_amdgcn_mfma_f32_32x32x16_bf16(kf_, qf1[dm_], st1_[s_], 0, 0, 0); \
      }                                                                           \
    }                                                                             \
    __builtin_amdgcn_s_setprio(0);                                                \
    if (DOPREV) PVONLY(P0, P1, V_lds[(ti_ - 1) & 1]);                             \
    float rs0_ = 0.f, rs1_ = 0.f;                                                 \
    _Pragma("unroll") for (int s_ = 0; s_ < 2; ++s_)                              \
    _Pragma("unroll") for (int j_ = 0; j_ < 8; ++j_) {                            \
      float a0_ = __builtin_amdgcn_exp2f(st0_[s_][2 * j_]);                       \
      float a1_ = __builtin_amdgcn_exp2f(st0_[s_][2 * j_ + 1]);                   \
      rs0_ += a0_ + a1_;                                                          \
      u32 wp0_;                                                                   \
      asm("v_cvt_pk_bf16_f32 %0, %1, %2" : "=v"(wp0_) : "v"(a0_), "v"(a1_));      \
      C0[s_ * 8 + j_] = wp0_;                                                     \
      float b0_ = __builtin_amdgcn_exp2f(st1_[s_][2 * j_]);                       \
      float b1_ = __builtin_amdgcn_exp2f(st1_[s_][2 * j_ + 1]);                   \
      rs1_ += b0_ + b1_;                                                          \
      u32 wp1_;                                                                   \
      asm("v_cvt_pk_bf16_f32 %0, %1, %2" : "=v"(wp1_) : "v"(b0_), "v"(b1_));      \
      C1[s_ * 8 + j_] = wp1_;                                                     \
    }                                                                             \
    lrow0 += rs0_;                                                                \
    lrow1 += rs1_;                                                                \
    asm volatile("s_waitcnt lgkmcnt(0)" ::: "memory");                            \
    __builtin_amdgcn_s_barrier();                                                 \
    __builtin_amdgcn_sched_barrier(0);                                            \
  }

  {  // prologue: stage K(kb)
    const char* kg0 = Kg + (size_t)kb * 64 * 2048;
    char* kl = (char*)K_lds[0] + ldsb;
    GLD16(kg0, kl);
    GLD16(kg0 + 32 * 2048, kl + 4096);
  }

  BODY(0, pkA0, pkA1, pkA0, pkA1, 0);
  for (int i = 1; i < NT - 1; i += 2) {
    BODY(i, pkB0, pkB1, pkA0, pkA1, 1);
    BODY(i + 1, pkA0, pkA1, pkB0, pkB1, 1);
  }
  BODY(NT - 1, pkB0, pkB1, pkA0, pkA1, 1);
  asm volatile("s_waitcnt vmcnt(0)" ::: "memory");
  __builtin_amdgcn_s_barrier();
  __builtin_amdgcn_sched_barrier(0);
  PVONLY(pkB0, pkB1, V_lds[(NT - 1) & 1]);

#undef BODY
#undef PVONLY

  lrow0 += __shfl_xor(lrow0, 32, 64);
  lrow1 += __shfl_xor(lrow1, 32, 64);
  if constexpr (SPLIT) {
    // bf16 unnormalized partials; z-stride = 4096*1024 u16 elements (8 MB)
    u16* or0 = Op + (size_t)z * (4096 * 1024) + (size_t)q0 * 1024 + h * 64 + hi * 4;
    u16* or1 = Op + (size_t)z * (4096 * 1024) + (size_t)q1 * 1024 + h * 64 + hi * 4;
#pragma unroll
    for (int a = 0; a < 2; ++a)
#pragma unroll
      for (int rr = 0; rr < 4; ++rr) {
        ushort4 o4;
        o4.x = f2bf(ot0[a][rr * 4 + 0]);
        o4.y = f2bf(ot0[a][rr * 4 + 1]);
        o4.z = f2bf(ot0[a][rr * 4 + 2]);
        o4.w = f2bf(ot0[a][rr * 4 + 3]);
        *(ushort4*)(or0 + a * 32 + rr * 8) = o4;
        o4.x = f2bf(ot1[a][rr * 4 + 0]);
        o4.y = f2bf(ot1[a][rr * 4 + 1]);
        o4.z = f2bf(ot1[a][rr * 4 + 2]);
        o4.w = f2bf(ot1[a][rr * 4 + 3]);
        *(ushort4*)(or1 + a * 32 + rr * 8) = o4;
      }
    if (hi == 0) {
      Lp[z * 65536 + h * 4096 + q0] = lrow0;
      Lp[z * 65536 + h * 4096 + q1] = lrow1;
    }
  } else {
    float inv0 = 1.f / lrow0, inv1 = 1.f / lrow1;
    u16* or0 = Ob + (size_t)q0 * 1024 + h * 64 + hi * 4;
    u16* or1 = Ob + (size_t)q1 * 1024 + h * 64 + hi * 4;
#pragma unroll
    for (int a = 0; a < 2; ++a)
#pragma unroll
      for (int rr = 0; rr < 4; ++rr) {
        ushort4 o4;
        o4.x = f2bf(ot0[a][rr * 4 + 0] * inv0);
        o4.y = f2bf(ot0[a][rr * 4 + 1] * inv0);
        o4.z = f2bf(ot0[a][rr * 4 + 2] * inv0);
        o4.w = f2bf(ot0[a][rr * 4 + 3] * inv0);
        *(ushort4*)(or0 + a * 32 + rr * 8) = o4;
        o4.x = f2bf(ot1[a][rr * 4 + 0] * inv1);
        o4.y = f2bf(ot1[a][rr * 4 + 1] * inv1);
        o4.z = f2bf(ot1[a][rr * 4 + 2] * inv1);
        o4.w = f2bf(ot1[a][rr * 4 + 3] * inv1);
        *(ushort4*)(or1 + a * 32 + rr * 8) = o4;
      }
  }
}

// ---------------- merge KV halves: Ob = (O0+O1)/(L0+L1), bf16 partials -> bf16 ----------------
__global__ __launch_bounds__(256) void merge_halves(const u16* __restrict__ O0,
                                                    const u16* __restrict__ O1,
                                                    const float* __restrict__ L0,
                                                    const float* __restrict__ L1,
                                                    u16* __restrict__ Ob) {
  int idx = blockIdx.x * 256 + threadIdx.x;  // 8 cols each
  int q = idx >> 7;
  int c0 = (idx & 127) * 8;
  int h = c0 >> 6;
  float inv = 1.f / (L0[h * 4096 + q] + L1[h * 4096 + q]);
  size_t off = (size_t)q * 1024 + c0;
  bf16x8 a = *(const bf16x8*)(O0 + off);
  bf16x8 b = *(const bf16x8*)(O1 + off);
  uint4 o;
#pragma unroll
  for (int k = 0; k < 4; ++k) {
    float s0 = (bf2f((u16)a[2 * k]) + bf2f((u16)b[2 * k])) * inv;
    float s1 = (bf2f((u16)a[2 * k + 1]) + bf2f((u16)b[2 * k + 1])) * inv;
    u32 pk = (u32)f2bf(s0) | ((u32)f2bf(s1) << 16);
    if (k == 0) o.x = pk;
    else if (k == 1) o.y = pk;
    else if (k == 2) o.z = pk;
    else o.w = pk;
  }
  *(uint4*)(Ob + off) = o;
}

extern "C" void kernel_launch(void* const* d_in, const int* in_sizes, int n_in,
                              void* d_out, int out_size, void* d_ws, size_t ws_size,
                              hipStream_t stream) {
  const float* x = (const float*)d_in[0];
  const float* Wq = (const float*)d_in[1];
  const float* Wk = (const float*)d_in[2];
  const float* Wv = (const float*)d_in[3];
  const float* Wo = (const float*)d_in[4];
  const float* bo = (const float*)d_in[5];
  float* out = (float*)d_out;

  char* ws = (char*)d_ws;
  u16* xb  = (u16*)(ws);                  // 8 MB (dead after gemm_qkv; reused as ObM)
  u16* Wqt = (u16*)(ws + (8u << 20));     // 2 MB  [Wqt|Wkt|Wvt] contiguous
  u16* Wot = (u16*)(ws + (14u << 20));    // 2 MB
  u16* Qb  = (u16*)(ws + (16u << 20));    // 8 MB
  u16* Kbf = (u16*)(ws + (24u << 20));    // 8 MB
  u16* Vth = (u16*)(ws + (32u << 20));    // 8 MB  [h][64][n] (quad-interleaved n)
  u16* Ob  = (u16*)(ws + (40u << 20));    // 8 MB (fallback path output)
  u16* Op  = (u16*)(ws + (40u << 20));    // 16 MB (split path: 2x bf16 partials, 8 MB each)
  float* Lp = (float*)(ws + (56u << 20)); // 512 KB (2x16x4096 f32)
  u16* Wkt = Wqt + (1u << 20);
  u16* Wvt = Wqt + (2u << 20);

  const bool split = ws_size >= ((56u << 20) + (1u << 19));

  prep<<<dim3(16, 16, 6), 256, 0, stream>>>(x, Wq, Wk, Wv, Wo, xb, Wqt, Wkt, Wvt, Wot);
  gemm_qkv<<<dim3(24, 32), 256, 0, stream>>>(xb, Wqt, Qb, Kbf, Vth);

  if (split) {
    flash_attn_t<1><<<dim3(16, 16, 2), 256, 0, stream>>>(Qb, Kbf, Vth, nullptr, Op, Lp);
    u16* ObM = (u16*)ws;  // reuse xb region
    merge_halves<<<2048, 256, 0, stream>>>(Op, Op + (1u << 22), Lp, Lp + 65536, ObM);
    gemm_out256<<<dim3(8, 32), 256, 0, stream>>>(ObM, Wot, out, bo);
  } else {
    flash_attn_t<0><<<dim3(16, 16, 1), 256, 0, stream>>>(Qb, Kbf, Vth, Ob, nullptr, nullptr);
    gemm_out256<<<dim3(8, 32), 256, 0, stream>>>(Ob, Wot, out, bo);
  }
}